// Round 8
// baseline (184.647 us; speedup 1.0000x reference)
//
#include <hip/hip_runtime.h>
#include <stdint.h>

#define H 8
#define DH 96
#define L 2048
#define NB 2
#define D 768

typedef unsigned short u16;
typedef unsigned int u32;
typedef __attribute__((ext_vector_type(8))) __bf16 bf16x8;
typedef __attribute__((ext_vector_type(4))) float f32x4;
typedef __attribute__((ext_vector_type(4))) u32 u32x4;
typedef __attribute__((ext_vector_type(2))) u32 u32x2;
typedef __attribute__((ext_vector_type(4))) u16 u16x4;

// softmax scale folded with log2(e): 96^-0.5 * 1.4426950408889634
#define QSCALE 0.14724444f

static __device__ __forceinline__ u16 f2bf(float f) {
  union { __bf16 h; u16 u; } v;
  v.h = (__bf16)f;
  return v.u;
}

static __device__ __forceinline__ bf16x8 cvt8r(f32x4 a, f32x4 b) {
  bf16x8 r;
  r[0] = (__bf16)a[0]; r[1] = (__bf16)a[1]; r[2] = (__bf16)a[2]; r[3] = (__bf16)a[3];
  r[4] = (__bf16)b[0]; r[5] = (__bf16)b[1]; r[6] = (__bf16)b[2]; r[7] = (__bf16)b[3];
  return r;
}

// ---------------------------------------------------------------------------
// Fused QKV projection + RoPE (z=0: Q, z=1: K, z=2: V->V^T)
// 384 threads: 4 compute waves (2x2 of 64x64) + 2 producer waves that do all
// global->reg->cvt->LDS staging. Double-buffered LDS, one barrier per K-step.
// ---------------------------------------------------------------------------
__global__ __launch_bounds__(384, 2)
void proj_qkv(const float* __restrict__ Qin, const float* __restrict__ Kin,
              const float* __restrict__ Vin,
              const float* __restrict__ Wq, const float* __restrict__ Wk,
              const float* __restrict__ Wv,
              const float* __restrict__ cq, const float* __restrict__ ck,
              u16* __restrict__ qo, u16* __restrict__ ko, u16* __restrict__ vo)
{
  __shared__ u16 a_lds[2][128 * 40];
  __shared__ u16 b_lds[2][128 * 40];
  const int tid = threadIdx.x;
  const int lane = tid & 63;
  const int w = tid >> 6;            // 0..3 compute, 4..5 producer
  const bool isProd = (tid >= 256);
  const int ptid = tid - 256;        // 0..127
  const int wr = w >> 1, wc = w & 1;
  const int z = blockIdx.z;
  const int row0 = blockIdx.y * 128;
  const int col0 = blockIdx.x * 128;

  const float* A = (z == 0) ? Qin : ((z == 1) ? Kin : Vin);
  const float* W = (z == 0) ? Wq : ((z == 1) ? Wk : Wv);

  f32x4 acc[4][4] = {};
  const int fr = lane & 15;
  const int fk = (lane >> 4) * 8;

  // producer addressing: thread covers rows (ptid>>2)+{0,32,64,96}, cols (ptid&3)*8..+7
  const int arow = ptid >> 2;
  const int acol = (ptid & 3) * 8;
  const float* pA = A + (size_t)(row0 + arow) * D + acol;
  const float* pW = W + (size_t)(col0 + arow) * D + acol;

  if (isProd) {  // prologue: stage k0=0 into buf 0
    f32x4 la[8], lb[8];
#pragma unroll
    for (int it = 0; it < 4; it++) {
      la[2 * it]     = *(const f32x4*)(pA + (size_t)it * 32 * D);
      la[2 * it + 1] = *(const f32x4*)(pA + (size_t)it * 32 * D + 4);
      lb[2 * it]     = *(const f32x4*)(pW + (size_t)it * 32 * D);
      lb[2 * it + 1] = *(const f32x4*)(pW + (size_t)it * 32 * D + 4);
    }
#pragma unroll
    for (int it = 0; it < 4; it++) {
      *(bf16x8*)(&a_lds[0][(arow + it * 32) * 40 + acol]) = cvt8r(la[2 * it], la[2 * it + 1]);
      *(bf16x8*)(&b_lds[0][(arow + it * 32) * 40 + acol]) = cvt8r(lb[2 * it], lb[2 * it + 1]);
    }
  }
  __syncthreads();

  int cur = 0;
  for (int k0 = 0; k0 < D; k0 += 32) {
    const int nk = k0 + 32;
    if (!isProd) {
      bf16x8 af[4], bfr[4];
#pragma unroll
      for (int m = 0; m < 4; m++)
        af[m] = *(const bf16x8*)(&a_lds[cur][(wr * 64 + m * 16 + fr) * 40 + fk]);
#pragma unroll
      for (int n = 0; n < 4; n++)
        bfr[n] = *(const bf16x8*)(&b_lds[cur][(wc * 64 + n * 16 + fr) * 40 + fk]);
#pragma unroll
      for (int m = 0; m < 4; m++)
#pragma unroll
        for (int n = 0; n < 4; n++)
          acc[m][n] = __builtin_amdgcn_mfma_f32_16x16x32_bf16(af[m], bfr[n], acc[m][n], 0, 0, 0);
    } else if (nk < D) {
      f32x4 la[8], lb[8];
#pragma unroll
      for (int it = 0; it < 4; it++) {
        la[2 * it]     = *(const f32x4*)(pA + (size_t)it * 32 * D + nk);
        la[2 * it + 1] = *(const f32x4*)(pA + (size_t)it * 32 * D + nk + 4);
        lb[2 * it]     = *(const f32x4*)(pW + (size_t)it * 32 * D + nk);
        lb[2 * it + 1] = *(const f32x4*)(pW + (size_t)it * 32 * D + nk + 4);
      }
#pragma unroll
      for (int it = 0; it < 4; it++) {
        *(bf16x8*)(&a_lds[cur ^ 1][(arow + it * 32) * 40 + acol]) = cvt8r(la[2 * it], la[2 * it + 1]);
        *(bf16x8*)(&b_lds[cur ^ 1][(arow + it * 32) * 40 + acol]) = cvt8r(lb[2 * it], lb[2 * it + 1]);
      }
    }
    __syncthreads();
    cur ^= 1;
  }

  if (isProd) return;

  if (z == 2) {
#pragma unroll
    for (int m = 0; m < 4; m++) {
      int rbase = row0 + wr * 64 + m * 16 + (lane >> 4) * 4;
#pragma unroll
      for (int n = 0; n < 4; n++) {
        int c = col0 + wc * 64 + n * 16 + fr;
        int hh = c / DH, dd = c % DH;
#pragma unroll
        for (int r = 0; r < 4; r++) {
          int row = rbase + r;
          int b = row >> 11, l = row & (L - 1);
          vo[((size_t)((b * H + hh) * DH + dd)) * L + l] = f2bf(acc[m][n][r]);
        }
      }
    }
  } else {
    const float* coords = (z == 0) ? cq : ck;
    u16* outp = (z == 0) ? qo : ko;
    const float postscale = (z == 0) ? QSCALE : 1.0f;
#pragma unroll
    for (int m = 0; m < 4; m++) {
      int rbase = row0 + wr * 64 + m * 16 + (lane >> 4) * 4;
#pragma unroll
      for (int np = 0; np < 2; np++) {
        int n1 = np * 2;
        int c1 = col0 + wc * 64 + n1 * 16 + fr;
        int hh = c1 / DH;
        int dd1 = c1 % DH;
        int axis = dd1 / 32;
        int j = dd1 & 15;
        float invf = exp2f(-(float)j * 0.83048202372184058f);
#pragma unroll
        for (int r = 0; r < 4; r++) {
          int row = rbase + r;
          int b = row >> 11, l = row & (L - 1);
          float coord = coords[((size_t)(b * L + l)) * 3 + axis];
          float ang = coord * invf;
          float sn = __sinf(ang), cs = __cosf(ang);
          float x1 = acc[m][n1][r], x2 = acc[m][n1 + 1][r];
          size_t base = ((size_t)((b * H + hh) * L + l)) * DH;
          outp[base + dd1] = f2bf((x1 * cs - x2 * sn) * postscale);
          outp[base + dd1 + 16] = f2bf((x1 * sn + x2 * cs) * postscale);
        }
      }
    }
  }
}

// ---------------------------------------------------------------------------
// Flash attention, producer/consumer: 384 threads = 4 compute waves (16 q-rows
// each, swapped-operand QK^T, lane-local softmax, P-from-regs PV) + 2 producer
// waves doing all K/V staging. Double-buffered LDS, one barrier per tile.
// Grid 512 blocks -> 2 blocks/CU -> 12 waves/CU.
// ---------------------------------------------------------------------------
#define KSTR 100
#define VSTR 68
#define NT   (L / 64)
__global__ __launch_bounds__(384, 2)
void attn_fwd(const u16* __restrict__ q_ws, const u16* __restrict__ k_ws,
              const u16* __restrict__ vt_ws, u16* __restrict__ ao)
{
  __shared__ u16 k_lds[2][64 * KSTR];
  __shared__ u16 vt_lds[2][96 * VSTR];
  const int tid = threadIdx.x;
  const int lane = tid & 63;
  const int w = tid >> 6;
  const bool isProd = (tid >= 256);
  const int ptid = tid - 256;  // 0..127
  const int bh = blockIdx.y;
  const int q0 = blockIdx.x * 64;

  const int fr = lane & 15;
  const int hi = lane >> 4;
  const int fko = hi * 8;

  const u16* kbase = k_ws + (size_t)bh * L * DH;
  const u16* vtbase = vt_ws + (size_t)bh * DH * L;

  // producer offsets: 6 K-chunks + 6 V-chunks per producer thread
  int kg[6], kl[6], vg[6], vl0[6], vl1[6];
  if (isProd) {
#pragma unroll
    for (int it = 0; it < 6; it++) {
      int ch = ptid + it * 128;          // 0..767
      int krow = ch / 12, koff = (ch % 12) * 8;
      kg[it] = krow * DH + koff;
      kl[it] = krow * KSTR + koff;
      int vrow = ch >> 3, vq = (ch & 7) * 2;
      vg[it] = vrow * L + vq * 4;
      int s0 = ((vq >> 3) << 5) | ((vq & 3) << 3) | (((vq >> 2) & 1) << 2);
      int vq1 = vq + 1;
      int s1 = ((vq1 >> 3) << 5) | ((vq1 & 3) << 3) | (((vq1 >> 2) & 1) << 2);
      vl0[it] = vrow * VSTR + s0;
      vl1[it] = vrow * VSTR + s1;
    }
  }

  // consumer state
  bf16x8 qf[3];
  f32x4 o[6] = {};
  float m_r = -1e30f, l_r = 0.f;
  if (!isProd) {
    const u16* qb = q_ws + ((size_t)bh * L + q0 + w * 16 + fr) * DH;
#pragma unroll
    for (int ks = 0; ks < 3; ks++)
      qf[ks] = *(const bf16x8*)(qb + ks * 32 + fko);
  }

  if (isProd) {  // prologue: tile 0 -> buf 0
    u32x4 kr[6], vr[6];
#pragma unroll
    for (int it = 0; it < 6; it++) {
      kr[it] = *(const u32x4*)(kbase + kg[it]);
      vr[it] = *(const u32x4*)(vtbase + vg[it]);
    }
#pragma unroll
    for (int it = 0; it < 6; it++) {
      *(u32x4*)(&k_lds[0][kl[it]]) = kr[it];
      u32x2 lo = { vr[it][0], vr[it][1] };
      u32x2 hi2 = { vr[it][2], vr[it][3] };
      *(u32x2*)(&vt_lds[0][vl0[it]]) = lo;
      *(u32x2*)(&vt_lds[0][vl1[it]]) = hi2;
    }
  }
  __syncthreads();

  int cur = 0;
  for (int t = 0; t < NT; t++) {
    if (!isProd) {
      // S^T = K Q^T : lane fr = q, s[kf][reg] at k = kf*16+hi*4+reg
      f32x4 s[4] = {};
#pragma unroll
      for (int ks = 0; ks < 3; ks++)
#pragma unroll
        for (int kf = 0; kf < 4; kf++) {
          bf16x8 kfrag = *(const bf16x8*)(&k_lds[cur][(kf * 16 + fr) * KSTR + ks * 32 + fko]);
          s[kf] = __builtin_amdgcn_mfma_f32_16x16x32_bf16(kfrag, qf[ks], s[kf], 0, 0, 0);
        }

      // lane-local online softmax (base-2; q pre-scaled)
      float mx = fmaxf(fmaxf(s[0][0], s[0][1]), fmaxf(s[0][2], s[0][3]));
#pragma unroll
      for (int kf = 1; kf < 4; kf++)
        mx = fmaxf(mx, fmaxf(fmaxf(s[kf][0], s[kf][1]), fmaxf(s[kf][2], s[kf][3])));
      mx = fmaxf(mx, __shfl_xor(mx, 16));
      mx = fmaxf(mx, __shfl_xor(mx, 32));
      float mn = fmaxf(m_r, mx);
      float alpha = exp2f(m_r - mn);
      m_r = mn;

      float p[4][4];
      float rs = 0.f;
#pragma unroll
      for (int kf = 0; kf < 4; kf++)
#pragma unroll
        for (int r = 0; r < 4; r++) {
          float pv = exp2f(s[kf][r] - mn);
          p[kf][r] = pv;
          rs += pv;
        }
      rs += __shfl_xor(rs, 16);
      rs += __shfl_xor(rs, 32);
      l_r = l_r * alpha + rs;

#pragma unroll
      for (int df = 0; df < 6; df++)
#pragma unroll
        for (int r = 0; r < 4; r++)
          o[df][r] *= alpha;

      bf16x8 pt[2];
#pragma unroll
      for (int ks = 0; ks < 2; ks++)
#pragma unroll
        for (int j = 0; j < 8; j++)
          pt[ks][j] = (__bf16)p[2 * ks + (j >> 2)][j & 3];

      // O^T += V P^T
#pragma unroll
      for (int ks = 0; ks < 2; ks++)
#pragma unroll
        for (int df = 0; df < 6; df++) {
          bf16x8 vfrag = *(const bf16x8*)(&vt_lds[cur][(df * 16 + fr) * VSTR + ks * 32 + fko]);
          o[df] = __builtin_amdgcn_mfma_f32_16x16x32_bf16(vfrag, pt[ks], o[df], 0, 0, 0);
        }
    } else if (t + 1 < NT) {
      const u16* kb = kbase + (size_t)(t + 1) * 64 * DH;
      const u16* vb = vtbase + (t + 1) * 64;
      u32x4 kr[6], vr[6];
#pragma unroll
      for (int it = 0; it < 6; it++) {
        kr[it] = *(const u32x4*)(kb + kg[it]);
        vr[it] = *(const u32x4*)(vb + vg[it]);
      }
#pragma unroll
      for (int it = 0; it < 6; it++) {
        *(u32x4*)(&k_lds[cur ^ 1][kl[it]]) = kr[it];
        u32x2 lo = { vr[it][0], vr[it][1] };
        u32x2 hi2 = { vr[it][2], vr[it][3] };
        *(u32x2*)(&vt_lds[cur ^ 1][vl0[it]]) = lo;
        *(u32x2*)(&vt_lds[cur ^ 1][vl1[it]]) = hi2;
      }
    }
    __syncthreads();
    cur ^= 1;
  }

  if (isProd) return;

  // epilogue: lane fr = q-row; 6 packed b64 stores
  const int b = bh >> 3, hh = bh & 7;
  const int l = q0 + w * 16 + fr;
  const float inv = 1.f / l_r;
  u16* aop = ao + ((size_t)(b * L + l)) * D + hh * DH + hi * 4;
#pragma unroll
  for (int df = 0; df < 6; df++) {
    u16x4 pk;
#pragma unroll
    for (int r = 0; r < 4; r++)
      pk[r] = f2bf(o[df][r] * inv);
    *(u16x4*)(aop + df * 16) = pk;
  }
}

// ---------------------------------------------------------------------------
// Output projection: out = AO @ Wo^T; 64x64 tiles, prefetch + dbuf LDS,
// one barrier per K-step.  (unchanged from r7)
// ---------------------------------------------------------------------------
__global__ __launch_bounds__(256, 2)
void gemm_out(const u16* __restrict__ A, const float* __restrict__ W,
              float* __restrict__ out)
{
  __shared__ u16 a_lds[2][64 * 40];
  __shared__ u16 b_lds[2][64 * 40];
  const int tid = threadIdx.x;
  const int lane = tid & 63;
  const int w = tid >> 6;
  const int wr = w >> 1, wc = w & 1;
  const int row0 = blockIdx.y * 64;
  const int col0 = blockIdx.x * 64;

  f32x4 acc[2][2] = {};
  const int srow = tid >> 2;
  const int scol = (tid & 3) * 8;
  const u16* pA = A + (size_t)(row0 + srow) * D + scol;
  const float* pW = W + (size_t)(col0 + srow) * D + scol;
  const int fr = lane & 15;
  const int fk = (lane >> 4) * 8;

  u32x4 ra;
  f32x4 rb0, rb1;
  ra  = *(const u32x4*)(pA);
  rb0 = *(const f32x4*)(pW);
  rb1 = *(const f32x4*)(pW + 4);
  *(u32x4*)(&a_lds[0][srow * 40 + scol]) = ra;
  *(bf16x8*)(&b_lds[0][srow * 40 + scol]) = cvt8r(rb0, rb1);
  __syncthreads();

  int cur = 0;
  for (int k0 = 0; k0 < D; k0 += 32) {
    const int nk = k0 + 32;
    if (nk < D) {
      ra  = *(const u32x4*)(pA + nk);
      rb0 = *(const f32x4*)(pW + nk);
      rb1 = *(const f32x4*)(pW + nk + 4);
    }
    bf16x8 af[2], bfr[2];
#pragma unroll
    for (int m = 0; m < 2; m++)
      af[m] = *(const bf16x8*)(&a_lds[cur][(wr * 32 + m * 16 + fr) * 40 + fk]);
#pragma unroll
    for (int n = 0; n < 2; n++)
      bfr[n] = *(const bf16x8*)(&b_lds[cur][(wc * 32 + n * 16 + fr) * 40 + fk]);
#pragma unroll
    for (int m = 0; m < 2; m++)
#pragma unroll
      for (int n = 0; n < 2; n++)
        acc[m][n] = __builtin_amdgcn_mfma_f32_16x16x32_bf16(af[m], bfr[n], acc[m][n], 0, 0, 0);
    if (nk < D) {
      *(u32x4*)(&a_lds[cur ^ 1][srow * 40 + scol]) = ra;
      *(bf16x8*)(&b_lds[cur ^ 1][srow * 40 + scol]) = cvt8r(rb0, rb1);
    }
    __syncthreads();
    cur ^= 1;
  }

#pragma unroll
  for (int m = 0; m < 2; m++) {
    int rbase = row0 + wr * 32 + m * 16 + (lane >> 4) * 4;
#pragma unroll
    for (int n = 0; n < 2; n++) {
      int c = col0 + wc * 32 + n * 16 + fr;
#pragma unroll
      for (int r = 0; r < 4; r++)
        out[(size_t)(rbase + r) * D + c] = acc[m][n][r];
    }
  }
}

extern "C" void kernel_launch(void* const* d_in, const int* in_sizes, int n_in,
                              void* d_out, int out_size, void* d_ws, size_t ws_size,
                              hipStream_t stream) {
  (void)in_sizes; (void)n_in; (void)out_size;
  const float* Qin = (const float*)d_in[0];
  const float* Kin = (const float*)d_in[1];
  const float* Vin = (const float*)d_in[2];
  const float* cq  = (const float*)d_in[3];
  const float* ck  = (const float*)d_in[4];
  const float* Wq  = (const float*)d_in[5];
  const float* Wk  = (const float*)d_in[6];
  const float* Wv  = (const float*)d_in[7];
  const float* Wo  = (const float*)d_in[8];
  float* out = (float*)d_out;

  const size_t per = (size_t)NB * H * L * DH;  // 3,145,728 elems
  if (ws_size < 4 * per * sizeof(u16)) return;

  u16* q_ws  = (u16*)d_ws;
  u16* k_ws  = q_ws + per;
  u16* vt_ws = k_ws + per;
  u16* ao_ws = vt_ws + per;

  proj_qkv<<<dim3(D / 128, (NB * L) / 128, 3), dim3(384), 0, stream>>>(
      Qin, Kin, Vin, Wq, Wk, Wv, cq, ck, q_ws, k_ws, vt_ws);
  attn_fwd<<<dim3(L / 64, NB * H), dim3(384), 0, stream>>>(q_ws, k_ws, vt_ws, ao_ws);
  gemm_out<<<dim3(D / 64, (NB * L) / 64), dim3(256), 0, stream>>>(ao_ws, Wo, out);
}

// Round 9
// 128.478 us; speedup vs baseline: 1.4372x; 1.4372x over previous
//
#include <hip/hip_runtime.h>
#include <stdint.h>

#define H 8
#define DH 96
#define L 2048
#define NB 2
#define D 768

typedef unsigned short u16;
typedef unsigned int u32;
typedef __attribute__((ext_vector_type(8))) __bf16 bf16x8;
typedef __attribute__((ext_vector_type(4))) float f32x4;
typedef __attribute__((ext_vector_type(4))) u32 u32x4;
typedef __attribute__((ext_vector_type(2))) u32 u32x2;
typedef __attribute__((ext_vector_type(4))) u16 u16x4;

// softmax scale folded with log2(e): 96^-0.5 * 1.4426950408889634
#define QSCALE 0.14724444f

static __device__ __forceinline__ u16 f2bf(float f) {
  union { __bf16 h; u16 u; } v;
  v.h = (__bf16)f;
  return v.u;
}

static __device__ __forceinline__ bf16x8 cvt8r(f32x4 a, f32x4 b) {
  bf16x8 r;
  r[0] = (__bf16)a[0]; r[1] = (__bf16)a[1]; r[2] = (__bf16)a[2]; r[3] = (__bf16)a[3];
  r[4] = (__bf16)b[0]; r[5] = (__bf16)b[1]; r[6] = (__bf16)b[2]; r[7] = (__bf16)b[3];
  return r;
}

// ---------------------------------------------------------------------------
// Fused QKV projection + RoPE (z=0: Q, z=1: K, z=2: V->V^T)
// 128x64 tiles (1152 blocks, ~3-4/CU) for latency hiding. 4 waves 2x2,
// wave-tile 64x32. Register-prefetch + dbuf LDS, one barrier per K-step.
// ---------------------------------------------------------------------------
__global__ __launch_bounds__(256, 3)
void proj_qkv(const float* __restrict__ Qin, const float* __restrict__ Kin,
              const float* __restrict__ Vin,
              const float* __restrict__ Wq, const float* __restrict__ Wk,
              const float* __restrict__ Wv,
              const float* __restrict__ cq, const float* __restrict__ ck,
              u16* __restrict__ qo, u16* __restrict__ ko, u16* __restrict__ vo)
{
  __shared__ u16 a_lds[2][128 * 40];
  __shared__ u16 b_lds[2][64 * 40];
  const int tid = threadIdx.x;
  const int lane = tid & 63;
  const int w = tid >> 6;
  const int wr = w >> 1, wc = w & 1;
  const int z = blockIdx.z;
  const int row0 = blockIdx.y * 128;
  const int col0 = blockIdx.x * 64;

  const float* A = (z == 0) ? Qin : ((z == 1) ? Kin : Vin);
  const float* W = (z == 0) ? Wq : ((z == 1) ? Wk : Wv);

  f32x4 acc[4][2] = {};
  const int fr = lane & 15;
  const int fk = (lane >> 4) * 8;

  // staging map: A 128x32 (16 f32/thread), W 64x32 (8 f32/thread)
  const int arow = tid >> 1;
  const int acol = (tid & 1) * 16;
  const int brow = tid >> 2;
  const int bcol = (tid & 3) * 8;
  const float* pA = A + (size_t)(row0 + arow) * D + acol;
  const float* pW = W + (size_t)(col0 + brow) * D + bcol;

  f32x4 la[4], lb[2];
  la[0] = *(const f32x4*)(pA);      la[1] = *(const f32x4*)(pA + 4);
  la[2] = *(const f32x4*)(pA + 8);  la[3] = *(const f32x4*)(pA + 12);
  lb[0] = *(const f32x4*)(pW);      lb[1] = *(const f32x4*)(pW + 4);
  *(bf16x8*)(&a_lds[0][arow * 40 + acol]) = cvt8r(la[0], la[1]);
  *(bf16x8*)(&a_lds[0][arow * 40 + acol + 8]) = cvt8r(la[2], la[3]);
  *(bf16x8*)(&b_lds[0][brow * 40 + bcol]) = cvt8r(lb[0], lb[1]);
  __syncthreads();

  int cur = 0;
  for (int k0 = 0; k0 < D; k0 += 32) {
    const int nk = k0 + 32;
    if (nk < D) {
      la[0] = *(const f32x4*)(pA + nk);      la[1] = *(const f32x4*)(pA + nk + 4);
      la[2] = *(const f32x4*)(pA + nk + 8);  la[3] = *(const f32x4*)(pA + nk + 12);
      lb[0] = *(const f32x4*)(pW + nk);      lb[1] = *(const f32x4*)(pW + nk + 4);
    }
    bf16x8 af[4], bfr[2];
#pragma unroll
    for (int m = 0; m < 4; m++)
      af[m] = *(const bf16x8*)(&a_lds[cur][(wr * 64 + m * 16 + fr) * 40 + fk]);
#pragma unroll
    for (int n = 0; n < 2; n++)
      bfr[n] = *(const bf16x8*)(&b_lds[cur][(wc * 32 + n * 16 + fr) * 40 + fk]);
#pragma unroll
    for (int m = 0; m < 4; m++)
#pragma unroll
      for (int n = 0; n < 2; n++)
        acc[m][n] = __builtin_amdgcn_mfma_f32_16x16x32_bf16(af[m], bfr[n], acc[m][n], 0, 0, 0);
    if (nk < D) {
      *(bf16x8*)(&a_lds[cur ^ 1][arow * 40 + acol]) = cvt8r(la[0], la[1]);
      *(bf16x8*)(&a_lds[cur ^ 1][arow * 40 + acol + 8]) = cvt8r(la[2], la[3]);
      *(bf16x8*)(&b_lds[cur ^ 1][brow * 40 + bcol]) = cvt8r(lb[0], lb[1]);
    }
    __syncthreads();
    cur ^= 1;
  }

  if (z == 2) {
#pragma unroll
    for (int m = 0; m < 4; m++) {
      int rbase = row0 + wr * 64 + m * 16 + (lane >> 4) * 4;
#pragma unroll
      for (int n = 0; n < 2; n++) {
        int c = col0 + wc * 32 + n * 16 + fr;
        int hh = c / DH, dd = c % DH;
#pragma unroll
        for (int r = 0; r < 4; r++) {
          int row = rbase + r;
          int b = row >> 11, l = row & (L - 1);
          vo[((size_t)((b * H + hh) * DH + dd)) * L + l] = f2bf(acc[m][n][r]);
        }
      }
    }
  } else {
    // RoPE: pair (n=0, n=1) at same lane; dd1%32 = fr < 16 always.
    const float* coords = (z == 0) ? cq : ck;
    u16* outp = (z == 0) ? qo : ko;
    const float postscale = (z == 0) ? QSCALE : 1.0f;
#pragma unroll
    for (int m = 0; m < 4; m++) {
      int rbase = row0 + wr * 64 + m * 16 + (lane >> 4) * 4;
      int c1 = col0 + wc * 32 + fr;
      int hh = c1 / DH;
      int dd1 = c1 % DH;
      int axis = dd1 / 32;
      int j = dd1 & 15;
      float invf = exp2f(-(float)j * 0.83048202372184058f);
#pragma unroll
      for (int r = 0; r < 4; r++) {
        int row = rbase + r;
        int b = row >> 11, l = row & (L - 1);
        float coord = coords[((size_t)(b * L + l)) * 3 + axis];
        float ang = coord * invf;
        float sn = __sinf(ang), cs = __cosf(ang);
        float x1 = acc[m][0][r], x2 = acc[m][1][r];
        size_t base = ((size_t)((b * H + hh) * L + l)) * DH;
        outp[base + dd1] = f2bf((x1 * cs - x2 * sn) * postscale);
        outp[base + dd1 + 16] = f2bf((x1 * sn + x2 * cs) * postscale);
      }
    }
  }
}

// ---------------------------------------------------------------------------
// Flash attention (r5 structure = measured best 63us) + one barrier per tile
// + T13 defer-max (skip cross-lane max/alpha unless needed) + deferred
// l-reduce (lane-local, reduced once in epilogue).
// 256 threads, 4 waves x 16 q-rows, swapped-operand QK^T, P-from-regs PV,
// in-wave register prefetch + dbuf K/V LDS.
// ---------------------------------------------------------------------------
#define KSTR 104
#define VSTR 72
#define NT   (L / 64)
__global__ __launch_bounds__(256, 2)
void attn_fwd(const u16* __restrict__ q_ws, const u16* __restrict__ k_ws,
              const u16* __restrict__ vt_ws, u16* __restrict__ ao)
{
  __shared__ u16 k_lds[2][64 * KSTR];
  __shared__ u16 vt_lds[2][96 * VSTR];
  const int tid = threadIdx.x;
  const int lane = tid & 63;
  const int w = tid >> 6;
  const int bh = blockIdx.y;
  const int q0 = blockIdx.x * 64;

  const int fr = lane & 15;
  const int hi = lane >> 4;
  const int fko = hi * 8;

  // staging offsets (K natural; V^T columns sigma-permuted in 4-chunks)
  int kg_off[3], kl_off[3], vg_off[3], vl0_off[3], vl1_off[3];
#pragma unroll
  for (int it = 0; it < 3; it++) {
    int ch = tid + it * 256;
    int krow = ch / 12, koff = (ch % 12) * 8;
    kg_off[it] = krow * DH + koff;
    kl_off[it] = krow * KSTR + koff;
    int vrow = ch >> 3, vq = (ch & 7) * 2;
    vg_off[it] = vrow * L + vq * 4;
    int s0 = ((vq >> 3) << 5) | ((vq & 3) << 3) | (((vq >> 2) & 1) << 2);
    int vq1 = vq + 1;
    int s1 = ((vq1 >> 3) << 5) | ((vq1 & 3) << 3) | (((vq1 >> 2) & 1) << 2);
    vl0_off[it] = vrow * VSTR + s0;
    vl1_off[it] = vrow * VSTR + s1;
  }

  // Q fragments (B-operand: lane fr = q-row)
  bf16x8 qf[3];
  const u16* qbase = q_ws + ((size_t)bh * L + q0 + w * 16 + fr) * DH;
#pragma unroll
  for (int ks = 0; ks < 3; ks++)
    qf[ks] = *(const bf16x8*)(qbase + ks * 32 + fko);

  f32x4 o[6] = {};
  float m_r = -1e30f, l_r = 0.f;

  const u16* kbase = k_ws + (size_t)bh * L * DH;
  const u16* vtbase = vt_ws + (size_t)bh * DH * L;

  u32x4 kreg[3], vreg[3];
#pragma unroll
  for (int it = 0; it < 3; it++) {
    kreg[it] = *(const u32x4*)(kbase + kg_off[it]);
    vreg[it] = *(const u32x4*)(vtbase + vg_off[it]);
  }
#pragma unroll
  for (int it = 0; it < 3; it++) {
    *(u32x4*)(&k_lds[0][kl_off[it]]) = kreg[it];
    u32x2 lo = { vreg[it][0], vreg[it][1] };
    u32x2 hi2 = { vreg[it][2], vreg[it][3] };
    *(u32x2*)(&vt_lds[0][vl0_off[it]]) = lo;
    *(u32x2*)(&vt_lds[0][vl1_off[it]]) = hi2;
  }
  __syncthreads();

  int cur = 0;
  for (int t = 0; t < NT; t++) {
    if (t + 1 < NT) {  // in-wave prefetch; latency hides under compute
      const u16* kb = kbase + (size_t)(t + 1) * 64 * DH;
      const u16* vb = vtbase + (t + 1) * 64;
#pragma unroll
      for (int it = 0; it < 3; it++) {
        kreg[it] = *(const u32x4*)(kb + kg_off[it]);
        vreg[it] = *(const u32x4*)(vb + vg_off[it]);
      }
    }

    // S^T = K Q^T : lane fr = q, s[kf][reg] at k = kf*16+hi*4+reg
    f32x4 s[4] = {};
#pragma unroll
    for (int ks = 0; ks < 3; ks++)
#pragma unroll
      for (int kf = 0; kf < 4; kf++) {
        bf16x8 kfrag = *(const bf16x8*)(&k_lds[cur][(kf * 16 + fr) * KSTR + ks * 32 + fko]);
        s[kf] = __builtin_amdgcn_mfma_f32_16x16x32_bf16(kfrag, qf[ks], s[kf], 0, 0, 0);
      }

    // T13 defer-max: lane-local max; cross-lane reduce + rescale only when
    // some row's local max exceeds the running max by > 8 (base-2 units).
    float pmax = fmaxf(fmaxf(s[0][0], s[0][1]), fmaxf(s[0][2], s[0][3]));
#pragma unroll
    for (int kf = 1; kf < 4; kf++)
      pmax = fmaxf(pmax, fmaxf(fmaxf(s[kf][0], s[kf][1]), fmaxf(s[kf][2], s[kf][3])));
    if (!__all(pmax - m_r <= 8.0f)) {
      float mx = fmaxf(pmax, __shfl_xor(pmax, 16));
      mx = fmaxf(mx, __shfl_xor(mx, 32));
      float mn = fmaxf(m_r, mx);
      float alpha = exp2f(m_r - mn);
      m_r = mn;
      l_r *= alpha;
#pragma unroll
      for (int df = 0; df < 6; df++)
#pragma unroll
        for (int r = 0; r < 4; r++)
          o[df][r] *= alpha;
    }

    float p[4][4];
    float rs = 0.f;
#pragma unroll
    for (int kf = 0; kf < 4; kf++)
#pragma unroll
      for (int r = 0; r < 4; r++) {
        float pv = exp2f(s[kf][r] - m_r);
        p[kf][r] = pv;
        rs += pv;
      }
    l_r += rs;  // lane-local; reduced in epilogue

    bf16x8 pt[2];
#pragma unroll
    for (int ks = 0; ks < 2; ks++)
#pragma unroll
      for (int j = 0; j < 8; j++)
        pt[ks][j] = (__bf16)p[2 * ks + (j >> 2)][j & 3];

    // O^T += V P^T
#pragma unroll
    for (int ks = 0; ks < 2; ks++)
#pragma unroll
      for (int df = 0; df < 6; df++) {
        bf16x8 vfrag = *(const bf16x8*)(&vt_lds[cur][(df * 16 + fr) * VSTR + ks * 32 + fko]);
        o[df] = __builtin_amdgcn_mfma_f32_16x16x32_bf16(vfrag, pt[ks], o[df], 0, 0, 0);
      }

    if (t + 1 < NT) {  // write buf last read at t-1 (ordered by prev barrier)
#pragma unroll
      for (int it = 0; it < 3; it++) {
        *(u32x4*)(&k_lds[cur ^ 1][kl_off[it]]) = kreg[it];
        u32x2 lo = { vreg[it][0], vreg[it][1] };
        u32x2 hi2 = { vreg[it][2], vreg[it][3] };
        *(u32x2*)(&vt_lds[cur ^ 1][vl0_off[it]]) = lo;
        *(u32x2*)(&vt_lds[cur ^ 1][vl1_off[it]]) = hi2;
      }
      __syncthreads();
      cur ^= 1;
    }
  }

  // epilogue: reduce l across the 4 hi-lanes of each q-row, then store
  float l_tot = l_r + __shfl_xor(l_r, 16);
  l_tot += __shfl_xor(l_tot, 32);
  const int b = bh >> 3, hh = bh & 7;
  const int l = q0 + w * 16 + fr;
  const float inv = 1.f / l_tot;
  u16* aop = ao + ((size_t)(b * L + l)) * D + hh * DH + hi * 4;
#pragma unroll
  for (int df = 0; df < 6; df++) {
    u16x4 pk;
#pragma unroll
    for (int r = 0; r < 4; r++)
      pk[r] = f2bf(o[df][r] * inv);
    *(u16x4*)(aop + df * 16) = pk;
  }
}

// ---------------------------------------------------------------------------
// Output projection: out = AO @ Wo^T; 64x64 tiles, prefetch + dbuf LDS,
// one barrier per K-step.
// ---------------------------------------------------------------------------
__global__ __launch_bounds__(256, 2)
void gemm_out(const u16* __restrict__ A, const float* __restrict__ W,
              float* __restrict__ out)
{
  __shared__ u16 a_lds[2][64 * 40];
  __shared__ u16 b_lds[2][64 * 40];
  const int tid = threadIdx.x;
  const int lane = tid & 63;
  const int w = tid >> 6;
  const int wr = w >> 1, wc = w & 1;
  const int row0 = blockIdx.y * 64;
  const int col0 = blockIdx.x * 64;

  f32x4 acc[2][2] = {};
  const int srow = tid >> 2;
  const int scol = (tid & 3) * 8;
  const u16* pA = A + (size_t)(row0 + srow) * D + scol;
  const float* pW = W + (size_t)(col0 + srow) * D + scol;
  const int fr = lane & 15;
  const int fk = (lane >> 4) * 8;

  u32x4 ra;
  f32x4 rb0, rb1;
  ra  = *(const u32x4*)(pA);
  rb0 = *(const f32x4*)(pW);
  rb1 = *(const f32x4*)(pW + 4);
  *(u32x4*)(&a_lds[0][srow * 40 + scol]) = ra;
  *(bf16x8*)(&b_lds[0][srow * 40 + scol]) = cvt8r(rb0, rb1);
  __syncthreads();

  int cur = 0;
  for (int k0 = 0; k0 < D; k0 += 32) {
    const int nk = k0 + 32;
    if (nk < D) {
      ra  = *(const u32x4*)(pA + nk);
      rb0 = *(const f32x4*)(pW + nk);
      rb1 = *(const f32x4*)(pW + nk + 4);
    }
    bf16x8 af[2], bfr[2];
#pragma unroll
    for (int m = 0; m < 2; m++)
      af[m] = *(const bf16x8*)(&a_lds[cur][(wr * 32 + m * 16 + fr) * 40 + fk]);
#pragma unroll
    for (int n = 0; n < 2; n++)
      bfr[n] = *(const bf16x8*)(&b_lds[cur][(wc * 32 + n * 16 + fr) * 40 + fk]);
#pragma unroll
    for (int m = 0; m < 2; m++)
#pragma unroll
      for (int n = 0; n < 2; n++)
        acc[m][n] = __builtin_amdgcn_mfma_f32_16x16x32_bf16(af[m], bfr[n], acc[m][n], 0, 0, 0);
    if (nk < D) {
      *(u32x4*)(&a_lds[cur ^ 1][srow * 40 + scol]) = ra;
      *(bf16x8*)(&b_lds[cur ^ 1][srow * 40 + scol]) = cvt8r(rb0, rb1);
    }
    __syncthreads();
    cur ^= 1;
  }

#pragma unroll
  for (int m = 0; m < 2; m++) {
    int rbase = row0 + wr * 32 + m * 16 + (lane >> 4) * 4;
#pragma unroll
    for (int n = 0; n < 2; n++) {
      int c = col0 + wc * 32 + n * 16 + fr;
#pragma unroll
      for (int r = 0; r < 4; r++)
        out[(size_t)(rbase + r) * D + c] = acc[m][n][r];
    }
  }
}

extern "C" void kernel_launch(void* const* d_in, const int* in_sizes, int n_in,
                              void* d_out, int out_size, void* d_ws, size_t ws_size,
                              hipStream_t stream) {
  (void)in_sizes; (void)n_in; (void)out_size;
  const float* Qin = (const float*)d_in[0];
  const float* Kin = (const float*)d_in[1];
  const float* Vin = (const float*)d_in[2];
  const float* cq  = (const float*)d_in[3];
  const float* ck  = (const float*)d_in[4];
  const float* Wq  = (const float*)d_in[5];
  const float* Wk  = (const float*)d_in[6];
  const float* Wv  = (const float*)d_in[7];
  const float* Wo  = (const float*)d_in[8];
  float* out = (float*)d_out;

  const size_t per = (size_t)NB * H * L * DH;  // 3,145,728 elems
  if (ws_size < 4 * per * sizeof(u16)) return;

  u16* q_ws  = (u16*)d_ws;
  u16* k_ws  = q_ws + per;
  u16* vt_ws = k_ws + per;
  u16* ao_ws = vt_ws + per;

  proj_qkv<<<dim3(D / 64, (NB * L) / 128, 3), dim3(256), 0, stream>>>(
      Qin, Kin, Vin, Wq, Wk, Wv, cq, ck, q_ws, k_ws, vt_ws);
  attn_fwd<<<dim3(L / 64, NB * H), dim3(256), 0, stream>>>(q_ws, k_ws, vt_ws, ao_ws);
  gemm_out<<<dim3(D / 64, (NB * L) / 64), dim3(256), 0, stream>>>(ao_ws, Wo, out);
}

// Round 10
// 115.460 us; speedup vs baseline: 1.5992x; 1.1127x over previous
//
#include <hip/hip_runtime.h>
#include <stdint.h>

#define H 8
#define DH 96
#define L 2048
#define NB 2
#define D 768

typedef unsigned short u16;
typedef unsigned int u32;
typedef __attribute__((ext_vector_type(8))) __bf16 bf16x8;
typedef __attribute__((ext_vector_type(4))) float f32x4;
typedef __attribute__((ext_vector_type(4))) u32 u32x4;
typedef __attribute__((ext_vector_type(2))) u32 u32x2;
typedef __attribute__((ext_vector_type(4))) u16 u16x4;

// softmax scale folded with log2(e): 96^-0.5 * 1.4426950408889634
#define QSCALE 0.14724444f

static __device__ __forceinline__ u16 f2bf(float f) {
  union { __bf16 h; u16 u; } v;
  v.h = (__bf16)f;
  return v.u;
}

static __device__ __forceinline__ bf16x8 cvt8r(f32x4 a, f32x4 b) {
  bf16x8 r;
  r[0] = (__bf16)a[0]; r[1] = (__bf16)a[1]; r[2] = (__bf16)a[2]; r[3] = (__bf16)a[3];
  r[4] = (__bf16)b[0]; r[5] = (__bf16)b[1]; r[6] = (__bf16)b[2]; r[7] = (__bf16)b[3];
  return r;
}

// ---------------------------------------------------------------------------
// Fused QKV projection + RoPE (z=0: Q, z=1: K, z=2: V->V^T)
// 128x64 tiles; XCD-swizzled 1D grid (col-tiles of one row-block share an
// XCD -> A-tile stays in that L2); 2-deep register prefetch + dbuf LDS,
// one barrier per K-step.
// ---------------------------------------------------------------------------
__global__ __launch_bounds__(256, 3)
void proj_qkv(const float* __restrict__ Qin, const float* __restrict__ Kin,
              const float* __restrict__ Vin,
              const float* __restrict__ Wq, const float* __restrict__ Wk,
              const float* __restrict__ Wv,
              const float* __restrict__ cq, const float* __restrict__ ck,
              u16* __restrict__ qo, u16* __restrict__ ko, u16* __restrict__ vo)
{
  __shared__ u16 a_lds[2][128 * 40];
  __shared__ u16 b_lds[2][64 * 40];
  const int tid = threadIdx.x;
  const int lane = tid & 63;
  const int w = tid >> 6;
  const int wr = w >> 1, wc = w & 1;

  // swizzle decode: col-tiles (bx) of one (by,z) share f%8 -> same XCD
  const int f = blockIdx.x;
  const int xr = f & 7;
  const int g = f >> 3;          // 0..143
  const int bx = g % 12;
  const int wq = g / 12;         // 0..11
  const int by = xr + 8 * (wq & 3);
  const int z = wq >> 2;
  const int row0 = by * 128;
  const int col0 = bx * 64;

  const float* A = (z == 0) ? Qin : ((z == 1) ? Kin : Vin);
  const float* W = (z == 0) ? Wq : ((z == 1) ? Wk : Wv);

  f32x4 acc[4][2] = {};
  const int fr = lane & 15;
  const int fk = (lane >> 4) * 8;

  // staging map: A 128x32 (16 f32/thread), W 64x32 (8 f32/thread)
  const int arow = tid >> 1;
  const int acol = (tid & 1) * 16;
  const int brow = tid >> 2;
  const int bcol = (tid & 3) * 8;
  const float* pA = A + (size_t)(row0 + arow) * D + acol;
  const float* pW = W + (size_t)(col0 + brow) * D + bcol;

  auto issueP = [&](int k, f32x4* la, f32x4* lb) {
#pragma unroll
    for (int i = 0; i < 4; i++) la[i] = *(const f32x4*)(pA + k + i * 4);
#pragma unroll
    for (int i = 0; i < 2; i++) lb[i] = *(const f32x4*)(pW + k + i * 4);
  };
  auto writeP = [&](int bi, const f32x4* la, const f32x4* lb) {
    *(bf16x8*)(&a_lds[bi][arow * 40 + acol]) = cvt8r(la[0], la[1]);
    *(bf16x8*)(&a_lds[bi][arow * 40 + acol + 8]) = cvt8r(la[2], la[3]);
    *(bf16x8*)(&b_lds[bi][brow * 40 + bcol]) = cvt8r(lb[0], lb[1]);
  };
  auto computeP = [&](int bi) {
    bf16x8 af[4], bfr[2];
#pragma unroll
    for (int m = 0; m < 4; m++)
      af[m] = *(const bf16x8*)(&a_lds[bi][(wr * 64 + m * 16 + fr) * 40 + fk]);
#pragma unroll
    for (int n = 0; n < 2; n++)
      bfr[n] = *(const bf16x8*)(&b_lds[bi][(wc * 32 + n * 16 + fr) * 40 + fk]);
#pragma unroll
    for (int m = 0; m < 4; m++)
#pragma unroll
      for (int n = 0; n < 2; n++)
        acc[m][n] = __builtin_amdgcn_mfma_f32_16x16x32_bf16(af[m], bfr[n], acc[m][n], 0, 0, 0);
  };

  f32x4 laA[4], lbA[2], laB[4], lbB[2];
  // prologue: tile k=0 via setB -> buf0; issue k=32 -> setA
  issueP(0, laB, lbB);
  writeP(0, laB, lbB);
  issueP(32, laA, lbA);
  __syncthreads();

  for (int k0 = 0; k0 < D; k0 += 64) {
    // even: tile k0 in buf0
    if (k0 + 64 < D) issueP(k0 + 64, laB, lbB);
    computeP(0);
    writeP(1, laA, lbA);          // tile k0+32 (always < D)
    __syncthreads();
    // odd: tile k0+32 in buf1
    if (k0 + 96 < D) issueP(k0 + 96, laA, lbA);
    computeP(1);
    if (k0 + 64 < D) writeP(0, laB, lbB);
    __syncthreads();
  }

  if (z == 2) {
#pragma unroll
    for (int m = 0; m < 4; m++) {
      int rbase = row0 + wr * 64 + m * 16 + (lane >> 4) * 4;
#pragma unroll
      for (int n = 0; n < 2; n++) {
        int c = col0 + wc * 32 + n * 16 + fr;
        int hh = c / DH, dd = c % DH;
#pragma unroll
        for (int r = 0; r < 4; r++) {
          int row = rbase + r;
          int b = row >> 11, l = row & (L - 1);
          vo[((size_t)((b * H + hh) * DH + dd)) * L + l] = f2bf(acc[m][n][r]);
        }
      }
    }
  } else {
    // RoPE: pair (n=0, n=1) at same lane; dd1%32 = fr < 16 always.
    const float* coords = (z == 0) ? cq : ck;
    u16* outp = (z == 0) ? qo : ko;
    const float postscale = (z == 0) ? QSCALE : 1.0f;
#pragma unroll
    for (int m = 0; m < 4; m++) {
      int rbase = row0 + wr * 64 + m * 16 + (lane >> 4) * 4;
      int c1 = col0 + wc * 32 + fr;
      int hh = c1 / DH;
      int dd1 = c1 % DH;
      int axis = dd1 / 32;
      int j = dd1 & 15;
      float invf = exp2f(-(float)j * 0.83048202372184058f);
#pragma unroll
      for (int r = 0; r < 4; r++) {
        int row = rbase + r;
        int b = row >> 11, l = row & (L - 1);
        float coord = coords[((size_t)(b * L + l)) * 3 + axis];
        float ang = coord * invf;
        float sn = __sinf(ang), cs = __cosf(ang);
        float x1 = acc[m][0][r], x2 = acc[m][1][r];
        size_t base = ((size_t)((b * H + hh) * L + l)) * DH;
        outp[base + dd1] = f2bf((x1 * cs - x2 * sn) * postscale);
        outp[base + dd1 + 16] = f2bf((x1 * sn + x2 * cs) * postscale);
      }
    }
  }
}

// ---------------------------------------------------------------------------
// Flash attention (r9 structure) + XCD-swizzled grid (q-tiles of one (b,h)
// share an XCD -> K/V L2-resident) + 2-deep register prefetch.
// ---------------------------------------------------------------------------
#define KSTR 104
#define VSTR 72
#define NT   (L / 64)
__global__ __launch_bounds__(256, 2)
void attn_fwd(const u16* __restrict__ q_ws, const u16* __restrict__ k_ws,
              const u16* __restrict__ vt_ws, u16* __restrict__ ao)
{
  __shared__ u16 k_lds[2][64 * KSTR];
  __shared__ u16 vt_lds[2][96 * VSTR];
  const int tid = threadIdx.x;
  const int lane = tid & 63;
  const int w = tid >> 6;

  // swizzle decode: q-tiles of one bh share f%8 -> same XCD
  const int f = blockIdx.x;
  const int xr = f & 7;
  const int g = f >> 3;          // 0..63
  const int qx = g & 31;
  const int bh = xr + 8 * (g >> 5);
  const int q0 = qx * 64;

  const int fr = lane & 15;
  const int hi = lane >> 4;
  const int fko = hi * 8;

  // staging offsets (K natural; V^T columns sigma-permuted in 4-chunks)
  int kg_off[3], kl_off[3], vg_off[3], vl0_off[3], vl1_off[3];
#pragma unroll
  for (int it = 0; it < 3; it++) {
    int ch = tid + it * 256;
    int krow = ch / 12, koff = (ch % 12) * 8;
    kg_off[it] = krow * DH + koff;
    kl_off[it] = krow * KSTR + koff;
    int vrow = ch >> 3, vq = (ch & 7) * 2;
    vg_off[it] = vrow * L + vq * 4;
    int s0 = ((vq >> 3) << 5) | ((vq & 3) << 3) | (((vq >> 2) & 1) << 2);
    int vq1 = vq + 1;
    int s1 = ((vq1 >> 3) << 5) | ((vq1 & 3) << 3) | (((vq1 >> 2) & 1) << 2);
    vl0_off[it] = vrow * VSTR + s0;
    vl1_off[it] = vrow * VSTR + s1;
  }

  // Q fragments (B-operand: lane fr = q-row)
  bf16x8 qf[3];
  const u16* qbase = q_ws + ((size_t)bh * L + q0 + w * 16 + fr) * DH;
#pragma unroll
  for (int ks = 0; ks < 3; ks++)
    qf[ks] = *(const bf16x8*)(qbase + ks * 32 + fko);

  f32x4 o[6] = {};
  float m_r = -1e30f, l_r = 0.f;

  const u16* kbase = k_ws + (size_t)bh * L * DH;
  const u16* vtbase = vt_ws + (size_t)bh * DH * L;

  auto kissue = [&](int t, u32x4* kr, u32x4* vr) {
    const u16* kb = kbase + (size_t)t * 64 * DH;
    const u16* vb = vtbase + t * 64;
#pragma unroll
    for (int it = 0; it < 3; it++) {
      kr[it] = *(const u32x4*)(kb + kg_off[it]);
      vr[it] = *(const u32x4*)(vb + vg_off[it]);
    }
  };
  auto kwrite = [&](int bi, const u32x4* kr, const u32x4* vr) {
#pragma unroll
    for (int it = 0; it < 3; it++) {
      *(u32x4*)(&k_lds[bi][kl_off[it]]) = kr[it];
      u32x2 lo = { vr[it][0], vr[it][1] };
      u32x2 hi2 = { vr[it][2], vr[it][3] };
      *(u32x2*)(&vt_lds[bi][vl0_off[it]]) = lo;
      *(u32x2*)(&vt_lds[bi][vl1_off[it]]) = hi2;
    }
  };
  auto attn_step = [&](int bi) {
    // S^T = K Q^T : lane fr = q, s[kf][reg] at k = kf*16+hi*4+reg
    f32x4 s[4] = {};
#pragma unroll
    for (int ks = 0; ks < 3; ks++)
#pragma unroll
      for (int kf = 0; kf < 4; kf++) {
        bf16x8 kfrag = *(const bf16x8*)(&k_lds[bi][(kf * 16 + fr) * KSTR + ks * 32 + fko]);
        s[kf] = __builtin_amdgcn_mfma_f32_16x16x32_bf16(kfrag, qf[ks], s[kf], 0, 0, 0);
      }
    // T13 defer-max
    float pmax = fmaxf(fmaxf(s[0][0], s[0][1]), fmaxf(s[0][2], s[0][3]));
#pragma unroll
    for (int kf = 1; kf < 4; kf++)
      pmax = fmaxf(pmax, fmaxf(fmaxf(s[kf][0], s[kf][1]), fmaxf(s[kf][2], s[kf][3])));
    if (!__all(pmax - m_r <= 8.0f)) {
      float mx = fmaxf(pmax, __shfl_xor(pmax, 16));
      mx = fmaxf(mx, __shfl_xor(mx, 32));
      float mn = fmaxf(m_r, mx);
      float alpha = exp2f(m_r - mn);
      m_r = mn;
      l_r *= alpha;
#pragma unroll
      for (int df = 0; df < 6; df++)
#pragma unroll
        for (int r = 0; r < 4; r++)
          o[df][r] *= alpha;
    }
    float p[4][4];
    float rs = 0.f;
#pragma unroll
    for (int kf = 0; kf < 4; kf++)
#pragma unroll
      for (int r = 0; r < 4; r++) {
        float pv = exp2f(s[kf][r] - m_r);
        p[kf][r] = pv;
        rs += pv;
      }
    l_r += rs;  // lane-local; reduced in epilogue
    bf16x8 pt[2];
#pragma unroll
    for (int ks = 0; ks < 2; ks++)
#pragma unroll
      for (int j = 0; j < 8; j++)
        pt[ks][j] = (__bf16)p[2 * ks + (j >> 2)][j & 3];
#pragma unroll
    for (int ks = 0; ks < 2; ks++)
#pragma unroll
      for (int df = 0; df < 6; df++) {
        bf16x8 vfrag = *(const bf16x8*)(&vt_lds[bi][(df * 16 + fr) * VSTR + ks * 32 + fko]);
        o[df] = __builtin_amdgcn_mfma_f32_16x16x32_bf16(vfrag, pt[ks], o[df], 0, 0, 0);
      }
  };

  u32x4 krA[3], vrA[3], krB[3], vrB[3];
  // prologue: tile0 via setB -> buf0; issue tile1 -> setA
  kissue(0, krB, vrB);
  kwrite(0, krB, vrB);
  kissue(1, krA, vrA);
  __syncthreads();

  for (int t = 0; t < NT; t += 2) {
    // even: tile t in buf0
    if (t + 2 < NT) kissue(t + 2, krB, vrB);
    attn_step(0);
    kwrite(1, krA, vrA);           // tile t+1 (always < NT)
    __syncthreads();
    // odd: tile t+1 in buf1
    if (t + 3 < NT) kissue(t + 3, krA, vrA);
    attn_step(1);
    if (t + 2 < NT) kwrite(0, krB, vrB);
    __syncthreads();
  }

  // epilogue: reduce l across the 4 hi-lanes of each q-row, then store
  float l_tot = l_r + __shfl_xor(l_r, 16);
  l_tot += __shfl_xor(l_tot, 32);
  const int b = bh >> 3, hh = bh & 7;
  const int l = q0 + w * 16 + fr;
  const float inv = 1.f / l_tot;
  u16* aop = ao + ((size_t)(b * L + l)) * D + hh * DH + hi * 4;
#pragma unroll
  for (int df = 0; df < 6; df++) {
    u16x4 pk;
#pragma unroll
    for (int r = 0; r < 4; r++)
      pk[r] = f2bf(o[df][r] * inv);
    *(u16x4*)(aop + df * 16) = pk;
  }
}

// ---------------------------------------------------------------------------
// Output projection: out = AO @ Wo^T; 64x64 tiles, XCD swizzle, 2-deep
// prefetch + dbuf LDS, one barrier per K-step.
// ---------------------------------------------------------------------------
__global__ __launch_bounds__(256, 2)
void gemm_out(const u16* __restrict__ A, const float* __restrict__ W,
              float* __restrict__ out)
{
  __shared__ u16 a_lds[2][64 * 40];
  __shared__ u16 b_lds[2][64 * 40];
  const int tid = threadIdx.x;
  const int lane = tid & 63;
  const int w = tid >> 6;
  const int wr = w >> 1, wc = w & 1;

  // swizzle decode: col-tiles of one row-block share f%8 -> same XCD
  const int f = blockIdx.x;
  const int xr = f & 7;
  const int g = f >> 3;          // 0..95
  const int bx = g % 12;
  const int wq = g / 12;         // 0..7
  const int by = xr + 8 * wq;    // 0..63
  const int row0 = by * 64;
  const int col0 = bx * 64;

  f32x4 acc[2][2] = {};
  const int srow = tid >> 2;
  const int scol = (tid & 3) * 8;
  const u16* pA = A + (size_t)(row0 + srow) * D + scol;
  const float* pW = W + (size_t)(col0 + srow) * D + scol;
  const int fr = lane & 15;
  const int fk = (lane >> 4) * 8;

  auto issueG = [&](int k, u32x4* ra, f32x4* rb) {
    ra[0] = *(const u32x4*)(pA + k);
    rb[0] = *(const f32x4*)(pW + k);
    rb[1] = *(const f32x4*)(pW + k + 4);
  };
  auto writeG = [&](int bi, const u32x4* ra, const f32x4* rb) {
    *(u32x4*)(&a_lds[bi][srow * 40 + scol]) = ra[0];
    *(bf16x8*)(&b_lds[bi][srow * 40 + scol]) = cvt8r(rb[0], rb[1]);
  };
  auto computeG = [&](int bi) {
    bf16x8 af[2], bfr[2];
#pragma unroll
    for (int m = 0; m < 2; m++)
      af[m] = *(const bf16x8*)(&a_lds[bi][(wr * 32 + m * 16 + fr) * 40 + fk]);
#pragma unroll
    for (int n = 0; n < 2; n++)
      bfr[n] = *(const bf16x8*)(&b_lds[bi][(wc * 32 + n * 16 + fr) * 40 + fk]);
#pragma unroll
    for (int m = 0; m < 2; m++)
#pragma unroll
      for (int n = 0; n < 2; n++)
        acc[m][n] = __builtin_amdgcn_mfma_f32_16x16x32_bf16(af[m], bfr[n], acc[m][n], 0, 0, 0);
  };

  u32x4 raA[1], raB[1];
  f32x4 rbA[2], rbB[2];
  issueG(0, raB, rbB);
  writeG(0, raB, rbB);
  issueG(32, raA, rbA);
  __syncthreads();

  for (int k0 = 0; k0 < D; k0 += 64) {
    if (k0 + 64 < D) issueG(k0 + 64, raB, rbB);
    computeG(0);
    writeG(1, raA, rbA);
    __syncthreads();
    if (k0 + 96 < D) issueG(k0 + 96, raA, rbA);
    computeG(1);
    if (k0 + 64 < D) writeG(0, raB, rbB);
    __syncthreads();
  }

#pragma unroll
  for (int m = 0; m < 2; m++) {
    int rbase = row0 + wr * 32 + m * 16 + (lane >> 4) * 4;
#pragma unroll
    for (int n = 0; n < 2; n++) {
      int c = col0 + wc * 32 + n * 16 + fr;
#pragma unroll
      for (int r = 0; r < 4; r++)
        out[(size_t)(rbase + r) * D + c] = acc[m][n][r];
    }
  }
}

extern "C" void kernel_launch(void* const* d_in, const int* in_sizes, int n_in,
                              void* d_out, int out_size, void* d_ws, size_t ws_size,
                              hipStream_t stream) {
  (void)in_sizes; (void)n_in; (void)out_size;
  const float* Qin = (const float*)d_in[0];
  const float* Kin = (const float*)d_in[1];
  const float* Vin = (const float*)d_in[2];
  const float* cq  = (const float*)d_in[3];
  const float* ck  = (const float*)d_in[4];
  const float* Wq  = (const float*)d_in[5];
  const float* Wk  = (const float*)d_in[6];
  const float* Wv  = (const float*)d_in[7];
  const float* Wo  = (const float*)d_in[8];
  float* out = (float*)d_out;

  const size_t per = (size_t)NB * H * L * DH;  // 3,145,728 elems
  if (ws_size < 4 * per * sizeof(u16)) return;

  u16* q_ws  = (u16*)d_ws;
  u16* k_ws  = q_ws + per;
  u16* vt_ws = k_ws + per;
  u16* ao_ws = vt_ws + per;

  proj_qkv<<<dim3(12 * 32 * 3), dim3(256), 0, stream>>>(
      Qin, Kin, Vin, Wq, Wk, Wv, cq, ck, q_ws, k_ws, vt_ws);
  attn_fwd<<<dim3(32 * NB * H), dim3(256), 0, stream>>>(q_ws, k_ws, vt_ws, ao_ws);
  gemm_out<<<dim3(12 * 64), dim3(256), 0, stream>>>(ao_ws, Wo, out);
}